// Round 3
// baseline (208.162 us; speedup 1.0000x reference)
//
#include <hip/hip_runtime.h>

// x: [8, 1, 160, 160, 160] fp32; log_sigma: [3] fp32; out: scalar fp32.
// loss = -(sum over 3816 (axis,b,pair) of exp(-sq/(2*sigma_axis^2))) / 3816.
//
// R9: FIRE-AND-FORGET STAGING. Theory: diff3 (~70us, ~2.4 TB/s on 167MB) is
// MLP-capped — register-landing loads give only waves x outstanding x 16B
// ~= 2-3KB in flight per CU vs the ~8KB needed for peak read BW (the 75us
// poison fill hits 7 TB/s because stores don't wait). Fix: stage slices into
// LDS via __builtin_amdgcn_global_load_lds (vmcnt-counted, no landing VGPRs),
// triple-buffered, counted s_waitcnt vmcnt(3) + RAW s_barrier (T3/T4 recipe;
// __syncthreads in-loop would force the vmcnt(0) drain = the m97 stall).
// In-flight becomes ~2 phases x 10.9KB x 3 blocks ~= 65KB/CU.
// Retile: 2560 blocks x 320 threads, block = (b, ds 0..31, hc 0..9):
// 5 owned slices (+1 d-halo) x 16 owned rows (+1 h-halo row) x full W.
// Stage = 2 uniform rounds of 320x16B (rows 0-15) + 1 uniform dup-padded
// round (halo row; clamped for hc==9) -> per-wave vmcnt uniform (3/phase).
// All neighbor data from LDS: no shfl, no fixB. Thread owns rows 2rp,2rp+1.
// Also: reduce+final fused via atomicAdd (out zeroed by diff3; stream order
// makes it safe) -> 2 dispatches. Cooperative launch (R8) broke graph capture.

constexpr int WF = 160;                 // floats per row
constexpr int SLICEF = 160 * 160;       // floats per slice
constexpr long BSTRF = 160L * SLICEF;   // floats per batch
constexpr int NB = 8;
constexpr int NPAIR = 159;
constexpr int NKEY = 3 * NB * NPAIR;    // 3816
constexpr int SLOT = 184;               // floats/slot: [0,5)=D [5,21)=H [21,181)=W
constexpr int NTILE = NB * 32 * 10;     // 2560 blocks
constexpr int BUFF = 3840;              // floats per LDS slice buffer (15360 B, padded)
constexpr int NRED = 60;                // 60*64 = 3840 >= 3816 keys

__device__ __forceinline__ float sq4(const float4& a, const float4& c) {
    float e0 = a.x - c.x, e1 = a.y - c.y, e2 = a.z - c.z, e3 = a.w - c.w;
    return e0 * e0 + e1 * e1 + e2 * e2 + e3 * e3;
}

__device__ __forceinline__ void stage16(const float* g, float* l) {
    __builtin_amdgcn_global_load_lds(
        (const __attribute__((address_space(1))) void*)g,
        (__attribute__((address_space(3))) void*)l, 16, 0, 0);
}

// Stage one slice chunk: rows 0-15 (2 uniform rounds) + halo row 16 (1 uniform
// round, every wave writes a dup copy into pad; only wave0's lands in the real
// halo area [2560,2720)). hc==9: halo row OOB -> clamp src to row 0 (never read).
__device__ __forceinline__ void stage_slice(const float* gs, float* lb, int t, int hc) {
    stage16(gs + t * 4, lb + t * 4);
    stage16(gs + 1280 + t * 4, lb + 1280 + t * 4);
    const int hoff = (hc == 9) ? 0 : 2560;
    stage16(gs + hoff + (t % 40) * 4, lb + 2560 + t * 4);
}

// 2560 blocks x 320 threads. tile -> (b, ds, hc): d0=5ds (5 owned slices +
// d-halo), h0=16hc (16 owned rows + h-halo). Thread: c4=t%40, rp=t/40 owns
// rows 2rp, 2rp+1; h-halo pair via LDS row 2rp+2; w-boundary via LDS scalar.
__global__ __launch_bounds__(320, 4) void diff3_kernel(const float* __restrict__ x,
                                                       float* __restrict__ ws,
                                                       float* __restrict__ out) {
    __shared__ float ldsf[3 * BUFF];  // 46080 B; reused as reduce scratch after loop

    const int t = threadIdx.x;
    const int tile = blockIdx.x;
    const int b = tile / 320;
    const int r2 = tile % 320;
    const int ds = r2 / 10;
    const int hc = r2 % 10;
    const int d0 = ds * 5, h0 = hc * 16;
    const bool lastSeg = (ds == 31);

    const int c4 = t % 40;
    const int rp = t / 40;              // 0..7: rows 2rp, 2rp+1
    const int lane = t & 63;
    const int wv = t >> 6;
    const bool sOK = (c4 < 39);
    const bool hOK = !(hc == 9 && rp == 7);  // pair (h0+15, h0+16) valid?

    if (tile == 0 && t == 0) out[0] = 0.f;  // reduce_kernel accumulates after

    const float* gs0 = x + (size_t)b * BSTRF + (size_t)d0 * SLICEF + (size_t)h0 * WF;

    // prologue: stages 0,1 in flight (6 vmcnt ticks/wave)
    stage_slice(gs0, ldsf, t, hc);
    stage_slice(gs0 + SLICEF, ldsf + BUFF, t, hc);

    float aW[4] = {0.f, 0.f, 0.f, 0.f};
    float aH0 = 0.f, aH1 = 0.f;
    float aD[5] = {0.f, 0.f, 0.f, 0.f, 0.f};
    float4 p0, p1;

    const int r0 = 2 * rp, r1 = 2 * rp + 1;

#pragma unroll
    for (int it = 0; it < 5; ++it) {
        // wait for stage(it), leave stage(it+1) (if issued) in flight
        if (it < 4 || !lastSeg) {
            asm volatile("s_waitcnt vmcnt(3)" ::: "memory");
        } else {
            asm volatile("s_waitcnt vmcnt(0)" ::: "memory");
        }
        __builtin_amdgcn_s_barrier();       // raw: no vmcnt(0) drain
        __builtin_amdgcn_sched_barrier(0);
        // issue stage(it+2) (buffer freed by compute(it-1), fenced by barrier)
        if (it < 3 || (it == 3 && !lastSeg))
            stage_slice(gs0 + (size_t)(it + 2) * SLICEF, ldsf + ((it + 2) % 3) * BUFF, t, hc);

        // compute slice it from buf[it%3]
        const float* bp = ldsf + (it % 3) * BUFF;
        const float4* b4 = (const float4*)bp;
        const float4 v0 = b4[r0 * 40 + c4];
        const float4 v1 = b4[r1 * 40 + c4];
        float4 hv;
        if (hOK) hv = b4[(r0 + 2) * 40 + c4];
        float s0 = 0.f, s1 = 0.f;
        if (sOK) {
            s0 = bp[r0 * WF + 4 * c4 + 4];  // w-boundary partner .x
            s1 = bp[r1 * WF + 4 * c4 + 4];
        }

        float dw;
        dw = v0.y - v0.x; aW[0] += dw * dw;
        dw = v0.z - v0.y; aW[1] += dw * dw;
        dw = v0.w - v0.z; aW[2] += dw * dw;
        dw = v1.y - v1.x; aW[0] += dw * dw;
        dw = v1.z - v1.y; aW[1] += dw * dw;
        dw = v1.w - v1.z; aW[2] += dw * dw;
        if (sOK) {
            dw = s0 - v0.w; aW[3] += dw * dw;
            dw = s1 - v1.w; aW[3] += dw * dw;
        }
        aH0 += sq4(v1, v0);                 // pair h0+2rp
        if (hOK) aH1 += sq4(hv, v1);        // pair h0+2rp+1
        if (it > 0) aD[it - 1] += sq4(v0, p0) + sq4(v1, p1);
        p0 = v0; p1 = v1;
    }
    if (!lastSeg) {  // d-halo slice (staged into buf2): completes pair d0+4
        asm volatile("s_waitcnt vmcnt(0)" ::: "memory");
        __builtin_amdgcn_s_barrier();
        __builtin_amdgcn_sched_barrier(0);
        const float4* b4 = (const float4*)(ldsf + 2 * BUFF);
        aD[4] = sq4(b4[r0 * 40 + c4], p0) + sq4(b4[r1 * 40 + c4], p1);
    }

    // ---- flush: reuse ldsf[0..2140) as scratch. H [16][41] @0; D 5x5 @660; W [160][9] @700.
    __syncthreads();  // all compute done (implicit drain harmless here)
    ldsf[r0 * 41 + c4] = aH0;
    ldsf[r1 * 41 + c4] = aH1;
#pragma unroll
    for (int j = 0; j < 5; ++j) {
        float dd = aD[j];
        for (int off = 32; off > 0; off >>= 1) dd += __shfl_down(dd, off, 64);
        if (lane == 0) ldsf[660 + j * 5 + wv] = dd;
    }
#pragma unroll
    for (int j = 0; j < 4; ++j) ldsf[700 + (4 * c4 + j) * 9 + rp] = aW[j];
    __syncthreads();

    float* slot = ws + (size_t)tile * SLOT;
    if (t < 16) {
        float h = 0.f;
        for (int i = 0; i < 40; ++i) h += ldsf[t * 41 + i];
        slot[5 + t] = h;
    }
    if (t < 5) {
        float d = 0.f;
        for (int w2 = 0; w2 < 5; ++w2) d += ldsf[660 + t * 5 + w2];
        slot[t] = d;
    }
    if (t < 160) {
        float w = 0.f;
        for (int i = 0; i < 8; ++i) w += ldsf[700 + t * 9 + i];
        slot[21 + t] = w;
    }
}

// 60 blocks x 64 threads: one thread per (axis,b,pair); atomicAdd partials
// into out (zeroed by diff3; stream order guarantees visibility).
__global__ __launch_bounds__(64) void reduce_kernel(const float* __restrict__ ws,
                                                    const float* __restrict__ log_sigma,
                                                    float* __restrict__ out) {
    const int gk = blockIdx.x * 64 + threadIdx.x;
    float kv = 0.f;
    if (gk < NKEY) {
        const int a = gk / (NB * NPAIR);
        const int rem = gk % (NB * NPAIR);
        const int b = rem / NPAIR;
        const int k = rem % NPAIR;
        const float f = -0.5f * expf(-2.f * log_sigma[a]);  // -1/(2*sigma^2)
        const float* wsb = ws + (size_t)b * 320 * SLOT;
        float val = 0.f;
        if (a == 0) {        // D pair k: ds=k/5, j=k%5, sum over 10 hc
            const int dss = k / 5, j = k % 5;
            const float* p = wsb + (size_t)(dss * 10) * SLOT + j;
            for (int hcc = 0; hcc < 10; ++hcc) val += p[(size_t)hcc * SLOT];
        } else if (a == 1) { // H pair k: hc=k/16, kk=k%16, sum over 32 ds
            const int hcc = k / 16, kk = k % 16;
            const float* p = wsb + (size_t)hcc * SLOT + 5 + kk;
            for (int dss = 0; dss < 32; ++dss) val += p[(size_t)(dss * 10) * SLOT];
        } else {             // W pair k: sum over all 320 (ds,hc)
            const float* p = wsb + 21 + k;
            for (int i = 0; i < 320; ++i) val += p[(size_t)i * SLOT];
        }
        kv = expf(val * f);
    }
    for (int off = 32; off > 0; off >>= 1) kv += __shfl_down(kv, off, 64);
    if (threadIdx.x == 0) atomicAdd(out, -kv / (float)NKEY);
}

extern "C" void kernel_launch(void* const* d_in, const int* in_sizes, int n_in,
                              void* d_out, int out_size, void* d_ws, size_t ws_size,
                              hipStream_t stream) {
    const float* x = (const float*)d_in[0];
    const float* log_sigma = (const float*)d_in[1];
    float* out = (float*)d_out;
    float* ws = (float*)d_ws;

    diff3_kernel<<<NTILE, 320, 0, stream>>>(x, ws, out);
    reduce_kernel<<<NRED, 64, 0, stream>>>(ws, log_sigma, out);
}